// Round 1
// baseline (251.424 us; speedup 1.0000x reference)
//
#include <hip/hip_runtime.h>
#include <cstdint>
#include <cstddef>

// ---------------------------------------------------------------------------
// Criterion: loss_rank (CE over normalized class map) + ramp * loss_kd (KL of
// masked self-similarity softmaxes).  B=2048, E=512, C=16384, TAU=4, TEMP=.05
// ---------------------------------------------------------------------------

#define B_ROWS 2048
#define E_DIM  512
#define C_DIM  16384
#define TEMP_INV 20.0f

typedef __bf16 bf16x8 __attribute__((ext_vector_type(8)));
typedef float  f32x4  __attribute__((ext_vector_type(4)));

__device__ __forceinline__ unsigned short f2bf(float x) {
    unsigned int u = __float_as_uint(x);
    unsigned int r = (u + 0x7FFFu + ((u >> 16) & 1u)) >> 16;  // RNE
    return (unsigned short)r;
}

__device__ __forceinline__ void async16(const void* g, void* l) {
    __builtin_amdgcn_global_load_lds(
        (const __attribute__((address_space(1))) void*)g,
        (__attribute__((address_space(3))) void*)l, 16, 0, 0);
}

// ---------------------------------------------------------------------------
// class_map row L2-norm -> inv_norm[c]; w_bf16[c][e] = bf16(cm[c][e]*inv)
// one wave per row (E=512 -> 8 f32 per lane)
// ---------------------------------------------------------------------------
__global__ __launch_bounds__(256)
void norm_convert(const float* __restrict__ cm, unsigned short* __restrict__ wbf,
                  float* __restrict__ inv_norm) {
    int row  = blockIdx.x * 4 + (threadIdx.x >> 6);
    int lane = threadIdx.x & 63;
    const float4* r = (const float4*)(cm + (size_t)row * E_DIM);
    float4 v0 = r[lane * 2 + 0];
    float4 v1 = r[lane * 2 + 1];
    float ss = v0.x*v0.x + v0.y*v0.y + v0.z*v0.z + v0.w*v0.w
             + v1.x*v1.x + v1.y*v1.y + v1.z*v1.z + v1.w*v1.w;
    for (int m = 32; m; m >>= 1) ss += __shfl_xor(ss, m);
    float inv = 1.0f / sqrtf(ss);
    if (lane == 0) inv_norm[row] = inv;
    unsigned int p0 = (unsigned)f2bf(v0.x*inv) | ((unsigned)f2bf(v0.y*inv) << 16);
    unsigned int p1 = (unsigned)f2bf(v0.z*inv) | ((unsigned)f2bf(v0.w*inv) << 16);
    unsigned int p2 = (unsigned)f2bf(v1.x*inv) | ((unsigned)f2bf(v1.y*inv) << 16);
    unsigned int p3 = (unsigned)f2bf(v1.z*inv) | ((unsigned)f2bf(v1.w*inv) << 16);
    uint4 pk; pk.x = p0; pk.y = p1; pk.z = p2; pk.w = p3;
    *(uint4*)(wbf + (size_t)row * E_DIM + lane * 8) = pk;
}

// batch & teacher fp32 -> bf16 (each thread: 8 elements of both)
__global__ __launch_bounds__(256)
void conv_pair(const float* __restrict__ a, const float* __restrict__ b,
               unsigned short* __restrict__ oa, unsigned short* __restrict__ ob) {
    int idx = blockIdx.x * 256 + threadIdx.x;   // 131072 threads total
    {
        const float4* pa = (const float4*)a;
        float4 v0 = pa[idx * 2], v1 = pa[idx * 2 + 1];
        uint4 pk;
        pk.x = (unsigned)f2bf(v0.x) | ((unsigned)f2bf(v0.y) << 16);
        pk.y = (unsigned)f2bf(v0.z) | ((unsigned)f2bf(v0.w) << 16);
        pk.z = (unsigned)f2bf(v1.x) | ((unsigned)f2bf(v1.y) << 16);
        pk.w = (unsigned)f2bf(v1.z) | ((unsigned)f2bf(v1.w) << 16);
        ((uint4*)oa)[idx] = pk;
    }
    {
        const float4* pb = (const float4*)b;
        float4 v0 = pb[idx * 2], v1 = pb[idx * 2 + 1];
        uint4 pk;
        pk.x = (unsigned)f2bf(v0.x) | ((unsigned)f2bf(v0.y) << 16);
        pk.y = (unsigned)f2bf(v0.z) | ((unsigned)f2bf(v0.w) << 16);
        pk.z = (unsigned)f2bf(v1.x) | ((unsigned)f2bf(v1.y) << 16);
        pk.w = (unsigned)f2bf(v1.z) | ((unsigned)f2bf(v1.w) << 16);
        ((uint4*)ob)[idx] = pk;
    }
}

// ---------------------------------------------------------------------------
// bf16 MFMA GEMM, both operands row-major K-contiguous (C = A * B^T).
// 128x128 tile, BK=64, 4 waves, 4x4 mfma_f32_16x16x32_bf16 per wave.
// EPI=0: store raw fp32 dots to out[M x N].
// EPI=1: per-row (max, sumexp) partials over 64-col chunks -> float2 out.
// ---------------------------------------------------------------------------
#define BM 128
#define BN 128
#define BK 64

template <int EPI>
__global__ __launch_bounds__(256)
void gemm_bt(const unsigned short* __restrict__ A, const unsigned short* __restrict__ Bm,
             int K, int N, float* __restrict__ out, float scale) {
    __shared__ __align__(16) unsigned short lA[BM * BK];
    __shared__ __align__(16) unsigned short lB[BN * BK];
    int bx = blockIdx.x, by = blockIdx.y;
    int tid = threadIdx.x;
    int w = tid >> 6, lane = tid & 63;
    int wr = w >> 1, wc = w & 1;
    int q = lane >> 4, c = lane & 15;

    f32x4 acc[4][4] = {};

    const unsigned short* Abase = A + (size_t)(by * BM) * K;
    const unsigned short* Bbase = Bm + (size_t)(bx * BN) * K;

    for (int kt = 0; kt < K; kt += BK) {
        #pragma unroll
        for (int cc = 0; cc < 4; cc++) {
            int f = cc * 256 + tid;
            int row = f >> 3, kc = (f & 7) * 8;
            async16(Abase + (size_t)row * K + kt + kc, (char*)lA + (size_t)f * 16);
        }
        #pragma unroll
        for (int cc = 0; cc < 4; cc++) {
            int f = cc * 256 + tid;
            int row = f >> 3, kc = (f & 7) * 8;
            async16(Bbase + (size_t)row * K + kt + kc, (char*)lB + (size_t)f * 16);
        }
        __syncthreads();
        #pragma unroll
        for (int kk = 0; kk < BK; kk += 32) {
            bf16x8 af[4], bf[4];
            #pragma unroll
            for (int i = 0; i < 4; i++)
                af[i] = *(const bf16x8*)&lA[(wr * 64 + i * 16 + c) * BK + kk + q * 8];
            #pragma unroll
            for (int j = 0; j < 4; j++)
                bf[j] = *(const bf16x8*)&lB[(wc * 64 + j * 16 + c) * BK + kk + q * 8];
            #pragma unroll
            for (int i = 0; i < 4; i++)
                #pragma unroll
                for (int j = 0; j < 4; j++)
                    acc[i][j] = __builtin_amdgcn_mfma_f32_16x16x32_bf16(af[i], bf[j], acc[i][j], 0, 0, 0);
        }
        __syncthreads();
    }

    if (EPI == 0) {
        #pragma unroll
        for (int i = 0; i < 4; i++) {
            #pragma unroll
            for (int r = 0; r < 4; r++) {
                size_t row = (size_t)(by * BM + wr * 64 + i * 16 + q * 4 + r);
                float* o = out + row * N + bx * BN + wc * 64 + c;
                #pragma unroll
                for (int j = 0; j < 4; j++) o[j * 16] = acc[i][j][r];
            }
        }
    } else {
        int nch = N >> 6;
        float2* part = (float2*)out;
        #pragma unroll
        for (int i = 0; i < 4; i++) {
            #pragma unroll
            for (int r = 0; r < 4; r++) {
                int row = by * BM + wr * 64 + i * 16 + q * 4 + r;
                float z0 = acc[i][0][r] * scale, z1 = acc[i][1][r] * scale;
                float z2 = acc[i][2][r] * scale, z3 = acc[i][3][r] * scale;
                float mx = fmaxf(fmaxf(z0, z1), fmaxf(z2, z3));
                #pragma unroll
                for (int m = 1; m < 16; m <<= 1) mx = fmaxf(mx, __shfl_xor(mx, m));
                float s = __expf(z0 - mx) + __expf(z1 - mx) + __expf(z2 - mx) + __expf(z3 - mx);
                #pragma unroll
                for (int m = 1; m < 16; m <<= 1) s += __shfl_xor(s, m);
                if (c == 0) {
                    float2 v; v.x = mx; v.y = s;
                    part[(size_t)row * nch + bx * 2 + wc] = v;
                }
            }
        }
    }
}

// ---------------------------------------------------------------------------
// stage 2: merge 256 partials/row -> lse; exact fp32 label-logit dot;
// atomicAdd mean contribution.  One wave per row.
// ---------------------------------------------------------------------------
__global__ __launch_bounds__(256)
void rank_stage2(const float2* __restrict__ part, const float* __restrict__ batch,
                 const float* __restrict__ cm, const float* __restrict__ inv_norm,
                 const int* __restrict__ labels, float* __restrict__ acc) {
    int row  = blockIdx.x * 4 + (threadIdx.x >> 6);
    int lane = threadIdx.x & 63;
    const float2* p = part + (size_t)row * 256;
    float m[4], s[4];
    float M = -1e30f;
    #pragma unroll
    for (int t = 0; t < 4; t++) {
        float2 v = p[t * 64 + lane];
        m[t] = v.x; s[t] = v.y;
        M = fmaxf(M, v.x);
    }
    for (int msk = 32; msk; msk >>= 1) M = fmaxf(M, __shfl_xor(M, msk));
    float S = 0.f;
    #pragma unroll
    for (int t = 0; t < 4; t++) S += s[t] * __expf(m[t] - M);
    for (int msk = 32; msk; msk >>= 1) S += __shfl_xor(S, msk);
    float lse = M + logf(S);

    int li = labels[row];
    const float4* brow = (const float4*)(batch + (size_t)row * E_DIM);
    const float4* crow = (const float4*)(cm + (size_t)li * E_DIM);
    float d = 0.f;
    #pragma unroll
    for (int t = 0; t < 2; t++) {
        float4 a = brow[lane * 2 + t];
        float4 cv = crow[lane * 2 + t];
        d += a.x * cv.x + a.y * cv.y + a.z * cv.z + a.w * cv.w;
    }
    for (int msk = 32; msk; msk >>= 1) d += __shfl_xor(d, msk);
    float zl = d * inv_norm[li] * TEMP_INV;
    if (lane == 0) atomicAdd(acc + 0, (lse - zl) * (1.0f / (float)B_ROWS));
}

// ---------------------------------------------------------------------------
// KD: per row, masked-scale softmax of sim & tsim + KL.  One block per row.
// kl_i = U/St - (log St - log Ss),  U = sum e_t * ((zt-Mt)-(zs-Ms))
// ---------------------------------------------------------------------------
__global__ __launch_bounds__(256)
void kd_kernel(const float* __restrict__ sim, const float* __restrict__ tsim,
               const int* __restrict__ labels, float* __restrict__ acc) {
    __shared__ float redmax[2][4];
    __shared__ float redsum[3][4];
    int i = blockIdx.x;
    int tid = threadIdx.x;
    int w = tid >> 6, lane = tid & 63;
    int li = labels[i];
    const float* srow = sim + (size_t)i * B_ROWS;
    const float* trow = tsim + (size_t)i * B_ROWS;

    float a[8], b[8];
    float ms = -1e30f, mt = -1e30f;
    #pragma unroll
    for (int k = 0; k < 8; k++) {
        int j = tid + k * 256;
        float sc = (labels[j] == li) ? 0.25f : 0.125f;   // scale/TAU
        float zs = srow[j] * sc;
        float zt = trow[j] * sc;
        a[k] = zs; b[k] = zt;
        ms = fmaxf(ms, zs); mt = fmaxf(mt, zt);
    }
    for (int msk = 32; msk; msk >>= 1) { ms = fmaxf(ms, __shfl_xor(ms, msk)); mt = fmaxf(mt, __shfl_xor(mt, msk)); }
    if (lane == 0) { redmax[0][w] = ms; redmax[1][w] = mt; }
    __syncthreads();
    float Ms = fmaxf(fmaxf(redmax[0][0], redmax[0][1]), fmaxf(redmax[0][2], redmax[0][3]));
    float Mt = fmaxf(fmaxf(redmax[1][0], redmax[1][1]), fmaxf(redmax[1][2], redmax[1][3]));

    float Ss = 0.f, St = 0.f, U = 0.f;
    #pragma unroll
    for (int k = 0; k < 8; k++) {
        float ds = a[k] - Ms, dt = b[k] - Mt;
        float et = __expf(dt);
        Ss += __expf(ds);
        St += et;
        U  += et * (dt - ds);
    }
    for (int msk = 32; msk; msk >>= 1) { Ss += __shfl_xor(Ss, msk); St += __shfl_xor(St, msk); U += __shfl_xor(U, msk); }
    if (lane == 0) { redsum[0][w] = Ss; redsum[1][w] = St; redsum[2][w] = U; }
    __syncthreads();
    if (tid == 0) {
        float SsT = redsum[0][0] + redsum[0][1] + redsum[0][2] + redsum[0][3];
        float StT = redsum[1][0] + redsum[1][1] + redsum[1][2] + redsum[1][3];
        float UT  = redsum[2][0] + redsum[2][1] + redsum[2][2] + redsum[2][3];
        float kl = UT / StT - (logf(StT) - logf(SsT));
        atomicAdd(acc + 1, kl * (1.0f / (float)B_ROWS));
    }
}

__global__ void finalize_kernel(const float* __restrict__ acc, const int* __restrict__ epoch,
                                float* __restrict__ out) {
    float lr = acc[0], lk = acc[1];
    float ramp = ((float)epoch[0] / 150.0f) * 1.0f * 16.0f;  // ALPHA * TAU^2
    out[0] = lr + ramp * lk;
    out[1] = lr;
    out[2] = lk;
}

// ---------------------------------------------------------------------------
extern "C" void kernel_launch(void* const* d_in, const int* in_sizes, int n_in,
                              void* d_out, int out_size, void* d_ws, size_t ws_size,
                              hipStream_t stream) {
    const float* batch   = (const float*)d_in[0];
    const float* teacher = (const float*)d_in[1];
    const float* cm      = (const float*)d_in[2];
    const int*   labels  = (const int*)d_in[3];
    const int*   epoch   = (const int*)d_in[4];
    float* out = (float*)d_out;
    char* ws = (char*)d_ws;

    // workspace layout (all 256-aligned)
    float*          acc      = (float*)(ws + 0);                     // 256 B
    float*          inv_norm = (float*)(ws + 256);                   // 64 KB
    unsigned short* wbf      = (unsigned short*)(ws + 65792);        // 16 MB
    unsigned short* bbf      = (unsigned short*)(ws + 16843008);     // 2 MB
    unsigned short* tbf      = (unsigned short*)(ws + 18940160);     // 2 MB
    float*          part     = (float*)(ws + 21037312);              // 4 MB (float2[2048][256])
    float*          sim      = (float*)(ws + 25231616);              // 16 MB
    float*          tsim     = (float*)(ws + 42008832);              // 16 MB
    // total ~58.8 MB

    hipMemsetAsync(acc, 0, 256, stream);

    norm_convert<<<C_DIM / 4, 256, 0, stream>>>(cm, wbf, inv_norm);
    conv_pair<<<(B_ROWS * E_DIM / 8) / 256, 256, 0, stream>>>(batch, teacher, bbf, tbf);

    // logits GEMM with fused per-tile softmax partials
    gemm_bt<1><<<dim3(C_DIM / BN, B_ROWS / BM), 256, 0, stream>>>(
        bbf, wbf, E_DIM, C_DIM, part, TEMP_INV);

    // self-similarity GEMMs (raw dots)
    gemm_bt<0><<<dim3(B_ROWS / BN, B_ROWS / BM), 256, 0, stream>>>(
        bbf, bbf, E_DIM, B_ROWS, sim, 1.0f);
    gemm_bt<0><<<dim3(B_ROWS / BN, B_ROWS / BM), 256, 0, stream>>>(
        tbf, tbf, E_DIM, B_ROWS, tsim, 1.0f);

    rank_stage2<<<B_ROWS / 4, 256, 0, stream>>>((const float2*)part, batch, cm, inv_norm, labels, acc);
    kd_kernel<<<B_ROWS, 256, 0, stream>>>(sim, tsim, labels, acc);
    finalize_kernel<<<1, 1, 0, stream>>>(acc, epoch, out);
}

// Round 2
// 212.480 us; speedup vs baseline: 1.1833x; 1.1833x over previous
//
#include <hip/hip_runtime.h>
#include <cstdint>
#include <cstddef>

// ---------------------------------------------------------------------------
// Criterion: loss_rank (CE over normalized class map) + ramp * loss_kd (KL of
// masked self-similarity softmaxes).  B=2048, E=512, C=16384, TAU=4, TEMP=.05
// ---------------------------------------------------------------------------

#define B_ROWS 2048
#define E_DIM  512
#define C_DIM  16384
#define TEMP_INV 20.0f

typedef __bf16 bf16x8 __attribute__((ext_vector_type(8)));
typedef float  f32x4  __attribute__((ext_vector_type(4)));

__device__ __forceinline__ unsigned short f2bf(float x) {
    unsigned int u = __float_as_uint(x);
    unsigned int r = (u + 0x7FFFu + ((u >> 16) & 1u)) >> 16;  // RNE
    return (unsigned short)r;
}

__device__ __forceinline__ void async16(const void* g, void* l) {
    __builtin_amdgcn_global_load_lds(
        (const __attribute__((address_space(1))) void*)g,
        (__attribute__((address_space(3))) void*)l, 16, 0, 0);
}

// ---------------------------------------------------------------------------
// prep: blocks [0, C/4)        -> class_map row-norm + bf16 convert
//       blocks [C/4, C/4+512)  -> batch & teacher fp32 -> bf16
// ---------------------------------------------------------------------------
__global__ __launch_bounds__(256)
void prep_kernel(const float* __restrict__ cm, unsigned short* __restrict__ wbf,
                 float* __restrict__ inv_norm,
                 const float* __restrict__ batch, const float* __restrict__ teacher,
                 unsigned short* __restrict__ bbf, unsigned short* __restrict__ tbf) {
    if (blockIdx.x < C_DIM / 4) {
        int row  = blockIdx.x * 4 + (threadIdx.x >> 6);
        int lane = threadIdx.x & 63;
        const float4* r = (const float4*)(cm + (size_t)row * E_DIM);
        float4 v0 = r[lane * 2 + 0];
        float4 v1 = r[lane * 2 + 1];
        float ss = v0.x*v0.x + v0.y*v0.y + v0.z*v0.z + v0.w*v0.w
                 + v1.x*v1.x + v1.y*v1.y + v1.z*v1.z + v1.w*v1.w;
        for (int m = 32; m; m >>= 1) ss += __shfl_xor(ss, m);
        float inv = 1.0f / sqrtf(ss);
        if (lane == 0) inv_norm[row] = inv;
        uint4 pk;
        pk.x = (unsigned)f2bf(v0.x*inv) | ((unsigned)f2bf(v0.y*inv) << 16);
        pk.y = (unsigned)f2bf(v0.z*inv) | ((unsigned)f2bf(v0.w*inv) << 16);
        pk.z = (unsigned)f2bf(v1.x*inv) | ((unsigned)f2bf(v1.y*inv) << 16);
        pk.w = (unsigned)f2bf(v1.z*inv) | ((unsigned)f2bf(v1.w*inv) << 16);
        *(uint4*)(wbf + (size_t)row * E_DIM + lane * 8) = pk;
    } else {
        int idx = (blockIdx.x - C_DIM / 4) * 256 + threadIdx.x;  // 131072 threads
        {
            const float4* pa = (const float4*)batch;
            float4 v0 = pa[idx * 2], v1 = pa[idx * 2 + 1];
            uint4 pk;
            pk.x = (unsigned)f2bf(v0.x) | ((unsigned)f2bf(v0.y) << 16);
            pk.y = (unsigned)f2bf(v0.z) | ((unsigned)f2bf(v0.w) << 16);
            pk.z = (unsigned)f2bf(v1.x) | ((unsigned)f2bf(v1.y) << 16);
            pk.w = (unsigned)f2bf(v1.z) | ((unsigned)f2bf(v1.w) << 16);
            ((uint4*)bbf)[idx] = pk;
        }
        {
            const float4* pb = (const float4*)teacher;
            float4 v0 = pb[idx * 2], v1 = pb[idx * 2 + 1];
            uint4 pk;
            pk.x = (unsigned)f2bf(v0.x) | ((unsigned)f2bf(v0.y) << 16);
            pk.y = (unsigned)f2bf(v0.z) | ((unsigned)f2bf(v0.w) << 16);
            pk.z = (unsigned)f2bf(v1.x) | ((unsigned)f2bf(v1.y) << 16);
            pk.w = (unsigned)f2bf(v1.z) | ((unsigned)f2bf(v1.w) << 16);
            ((uint4*)tbf)[idx] = pk;
        }
    }
}

// ---------------------------------------------------------------------------
// bf16 MFMA GEMM core, C = A * B^T, both operands row-major K-contiguous.
// 128x128 tile, BK=64, 4 waves, 4x4 mfma_f32_16x16x32_bf16 per wave.
// LDS K-chunk XOR swizzle (chunk' = chunk ^ (row&7)) kills the 16-way bank
// conflict of the naive row*BK layout while staying global_load_lds-legal
// (we permute WHICH global chunk a lane fetches, not where it lands).
// EPI=0: store raw fp32 dots.  EPI=1: per-row (max,sumexp) over 64-col chunks.
// ---------------------------------------------------------------------------
#define BM 128
#define BN 128
#define BK 64

template <int EPI>
__device__ __forceinline__
void gemm_core(const unsigned short* __restrict__ A, const unsigned short* __restrict__ Bm,
               int K, int N, float* __restrict__ out, float scale,
               int bx, int by, unsigned short* lA, unsigned short* lB) {
    int tid = threadIdx.x;
    int w = tid >> 6, lane = tid & 63;
    int wr = w >> 1, wc = w & 1;
    int q = lane >> 4, c = lane & 15;

    f32x4 acc[4][4] = {};

    const unsigned short* Abase = A + (size_t)(by * BM) * K;
    const unsigned short* Bbase = Bm + (size_t)(bx * BN) * K;

    for (int kt = 0; kt < K; kt += BK) {
        #pragma unroll
        for (int cc = 0; cc < 4; cc++) {
            int f = cc * 256 + tid;
            int row = f >> 3, kcb = f & 7;
            int g = kcb ^ (row & 7);                       // swizzled source chunk
            async16(Abase + (size_t)row * K + kt + g * 8, (char*)lA + (size_t)f * 16);
        }
        #pragma unroll
        for (int cc = 0; cc < 4; cc++) {
            int f = cc * 256 + tid;
            int row = f >> 3, kcb = f & 7;
            int g = kcb ^ (row & 7);
            async16(Bbase + (size_t)row * K + kt + g * 8, (char*)lB + (size_t)f * 16);
        }
        __syncthreads();
        #pragma unroll
        for (int kk = 0; kk < BK; kk += 32) {
            int cb = (kk >> 3) + q;                        // logical chunk 0..7
            int sw = cb ^ (c & 7);                         // swizzled LDS chunk
            bf16x8 af[4], bfr[4];
            #pragma unroll
            for (int i = 0; i < 4; i++)
                af[i] = *(const bf16x8*)&lA[(wr * 64 + i * 16 + c) * BK + sw * 8];
            #pragma unroll
            for (int j = 0; j < 4; j++)
                bfr[j] = *(const bf16x8*)&lB[(wc * 64 + j * 16 + c) * BK + sw * 8];
            #pragma unroll
            for (int i = 0; i < 4; i++)
                #pragma unroll
                for (int j = 0; j < 4; j++)
                    acc[i][j] = __builtin_amdgcn_mfma_f32_16x16x32_bf16(af[i], bfr[j], acc[i][j], 0, 0, 0);
        }
        __syncthreads();
    }

    if (EPI == 0) {
        #pragma unroll
        for (int i = 0; i < 4; i++) {
            #pragma unroll
            for (int r = 0; r < 4; r++) {
                size_t row = (size_t)(by * BM + wr * 64 + i * 16 + q * 4 + r);
                float* o = out + row * N + bx * BN + wc * 64 + c;
                #pragma unroll
                for (int j = 0; j < 4; j++) o[j * 16] = acc[i][j][r];
            }
        }
    } else {
        int nch = N >> 6;
        float2* part = (float2*)out;
        #pragma unroll
        for (int i = 0; i < 4; i++) {
            #pragma unroll
            for (int r = 0; r < 4; r++) {
                int row = by * BM + wr * 64 + i * 16 + q * 4 + r;
                float z0 = acc[i][0][r] * scale, z1 = acc[i][1][r] * scale;
                float z2 = acc[i][2][r] * scale, z3 = acc[i][3][r] * scale;
                float mx = fmaxf(fmaxf(z0, z1), fmaxf(z2, z3));
                #pragma unroll
                for (int m = 1; m < 16; m <<= 1) mx = fmaxf(mx, __shfl_xor(mx, m));
                float s = __expf(z0 - mx) + __expf(z1 - mx) + __expf(z2 - mx) + __expf(z3 - mx);
                #pragma unroll
                for (int m = 1; m < 16; m <<= 1) s += __shfl_xor(s, m);
                if (c == 0) {
                    float2 v; v.x = mx; v.y = s;
                    part[(size_t)row * nch + bx * 2 + wc] = v;
                }
            }
        }
    }
}

__global__ __launch_bounds__(256)
void gemm_logits(const unsigned short* __restrict__ A, const unsigned short* __restrict__ Bm,
                 float* __restrict__ out) {
    __shared__ __align__(16) unsigned short lA[BM * BK];
    __shared__ __align__(16) unsigned short lB[BN * BK];
    gemm_core<1>(A, Bm, E_DIM, C_DIM, out, TEMP_INV, blockIdx.x, blockIdx.y, lA, lB);
}

// both self-similarity GEMMs in one dispatch (blockIdx.z selects operand)
__global__ __launch_bounds__(256)
void gemm_sims(const unsigned short* __restrict__ bbf, const unsigned short* __restrict__ tbf,
               float* __restrict__ sim, float* __restrict__ tsim) {
    __shared__ __align__(16) unsigned short lA[BM * BK];
    __shared__ __align__(16) unsigned short lB[BN * BK];
    const unsigned short* A = blockIdx.z ? tbf : bbf;
    float* out = blockIdx.z ? tsim : sim;
    gemm_core<0>(A, A, E_DIM, B_ROWS, out, 1.0f, blockIdx.x, blockIdx.y, lA, lB);
}

// ---------------------------------------------------------------------------
// reduce: blocks [0,512)      -> rank stage2 (merge partials + label logit)
//         blocks [512,2560)   -> KD row softmax/KL
// ---------------------------------------------------------------------------
__global__ __launch_bounds__(256)
void reduce_kernel(const float2* __restrict__ part, const float* __restrict__ batch,
                   const float* __restrict__ cm, const float* __restrict__ inv_norm,
                   const int* __restrict__ labels,
                   const float* __restrict__ sim, const float* __restrict__ tsim,
                   float* __restrict__ acc) {
    __shared__ float redmax[2][4];
    __shared__ float redsum[3][4];
    if (blockIdx.x < B_ROWS / 4) {
        int row  = blockIdx.x * 4 + (threadIdx.x >> 6);
        int lane = threadIdx.x & 63;
        const float2* p = part + (size_t)row * 256;
        float m[4], s[4];
        float M = -1e30f;
        #pragma unroll
        for (int t = 0; t < 4; t++) {
            float2 v = p[t * 64 + lane];
            m[t] = v.x; s[t] = v.y;
            M = fmaxf(M, v.x);
        }
        for (int msk = 32; msk; msk >>= 1) M = fmaxf(M, __shfl_xor(M, msk));
        float S = 0.f;
        #pragma unroll
        for (int t = 0; t < 4; t++) S += s[t] * __expf(m[t] - M);
        for (int msk = 32; msk; msk >>= 1) S += __shfl_xor(S, msk);
        float lse = M + logf(S);

        int li = labels[row];
        const float4* brow = (const float4*)(batch + (size_t)row * E_DIM);
        const float4* crow = (const float4*)(cm + (size_t)li * E_DIM);
        float d = 0.f;
        #pragma unroll
        for (int t = 0; t < 2; t++) {
            float4 a = brow[lane * 2 + t];
            float4 cv = crow[lane * 2 + t];
            d += a.x * cv.x + a.y * cv.y + a.z * cv.z + a.w * cv.w;
        }
        for (int msk = 32; msk; msk >>= 1) d += __shfl_xor(d, msk);
        float zl = d * inv_norm[li] * TEMP_INV;
        if (lane == 0) atomicAdd(acc + 0, (lse - zl) * (1.0f / (float)B_ROWS));
    } else {
        int i = blockIdx.x - B_ROWS / 4;
        int tid = threadIdx.x;
        int w = tid >> 6, lane = tid & 63;
        int li = labels[i];
        const float* srow = sim + (size_t)i * B_ROWS;
        const float* trow = tsim + (size_t)i * B_ROWS;

        float a[8], b[8];
        float ms = -1e30f, mt = -1e30f;
        #pragma unroll
        for (int k = 0; k < 8; k++) {
            int j = tid + k * 256;
            float sc = (labels[j] == li) ? 0.25f : 0.125f;   // scale/TAU
            float zs = srow[j] * sc;
            float zt = trow[j] * sc;
            a[k] = zs; b[k] = zt;
            ms = fmaxf(ms, zs); mt = fmaxf(mt, zt);
        }
        for (int msk = 32; msk; msk >>= 1) { ms = fmaxf(ms, __shfl_xor(ms, msk)); mt = fmaxf(mt, __shfl_xor(mt, msk)); }
        if (lane == 0) { redmax[0][w] = ms; redmax[1][w] = mt; }
        __syncthreads();
        float Ms = fmaxf(fmaxf(redmax[0][0], redmax[0][1]), fmaxf(redmax[0][2], redmax[0][3]));
        float Mt = fmaxf(fmaxf(redmax[1][0], redmax[1][1]), fmaxf(redmax[1][2], redmax[1][3]));

        float Ss = 0.f, St = 0.f, U = 0.f;
        #pragma unroll
        for (int k = 0; k < 8; k++) {
            float ds = a[k] - Ms, dt = b[k] - Mt;
            float et = __expf(dt);
            Ss += __expf(ds);
            St += et;
            U  += et * (dt - ds);
        }
        for (int msk = 32; msk; msk >>= 1) { Ss += __shfl_xor(Ss, msk); St += __shfl_xor(St, msk); U += __shfl_xor(U, msk); }
        if (lane == 0) { redsum[0][w] = Ss; redsum[1][w] = St; redsum[2][w] = U; }
        __syncthreads();
        if (tid == 0) {
            float SsT = redsum[0][0] + redsum[0][1] + redsum[0][2] + redsum[0][3];
            float StT = redsum[1][0] + redsum[1][1] + redsum[1][2] + redsum[1][3];
            float UT  = redsum[2][0] + redsum[2][1] + redsum[2][2] + redsum[2][3];
            float kl = UT / StT - (logf(StT) - logf(SsT));
            atomicAdd(acc + 1, kl * (1.0f / (float)B_ROWS));
        }
    }
}

__global__ void finalize_kernel(const float* __restrict__ acc, const int* __restrict__ epoch,
                                float* __restrict__ out) {
    float lr = acc[0], lk = acc[1];
    float ramp = ((float)epoch[0] / 150.0f) * 1.0f * 16.0f;  // ALPHA * TAU^2
    out[0] = lr + ramp * lk;
    out[1] = lr;
    out[2] = lk;
}

// ---------------------------------------------------------------------------
extern "C" void kernel_launch(void* const* d_in, const int* in_sizes, int n_in,
                              void* d_out, int out_size, void* d_ws, size_t ws_size,
                              hipStream_t stream) {
    const float* batch   = (const float*)d_in[0];
    const float* teacher = (const float*)d_in[1];
    const float* cm      = (const float*)d_in[2];
    const int*   labels  = (const int*)d_in[3];
    const int*   epoch   = (const int*)d_in[4];
    float* out = (float*)d_out;
    char* ws = (char*)d_ws;

    // workspace layout (all 256-aligned)
    float*          acc      = (float*)(ws + 0);                     // 256 B
    float*          inv_norm = (float*)(ws + 256);                   // 64 KB
    unsigned short* wbf      = (unsigned short*)(ws + 65792);        // 16 MB
    unsigned short* bbf      = (unsigned short*)(ws + 16843008);     // 2 MB
    unsigned short* tbf      = (unsigned short*)(ws + 18940160);     // 2 MB
    float*          part     = (float*)(ws + 21037312);              // 4 MB (float2[2048][256])
    float*          sim      = (float*)(ws + 25231616);              // 16 MB
    float*          tsim     = (float*)(ws + 42008832);              // 16 MB
    // total ~58.8 MB

    hipMemsetAsync(acc, 0, 256, stream);

    prep_kernel<<<C_DIM / 4 + 512, 256, 0, stream>>>(cm, wbf, inv_norm, batch, teacher, bbf, tbf);

    gemm_logits<<<dim3(C_DIM / BN, B_ROWS / BM), 256, 0, stream>>>(bbf, wbf, (float*)part);

    gemm_sims<<<dim3(B_ROWS / BN, B_ROWS / BM, 2), 256, 0, stream>>>(bbf, tbf, sim, tsim);

    reduce_kernel<<<B_ROWS / 4 + B_ROWS, 256, 0, stream>>>(
        (const float2*)part, batch, cm, inv_norm, labels, sim, tsim, acc);

    finalize_kernel<<<1, 1, 0, stream>>>(acc, epoch, out);
}

// Round 3
// 158.970 us; speedup vs baseline: 1.5816x; 1.3366x over previous
//
#include <hip/hip_runtime.h>
#include <cstdint>
#include <cstddef>

// ---------------------------------------------------------------------------
// Criterion: loss_rank (CE over normalized class map) + ramp * loss_kd (KL of
// masked self-similarity softmaxes).  B=2048, E=512, C=16384, TAU=4, TEMP=.05
// ---------------------------------------------------------------------------

#define B_ROWS 2048
#define E_DIM  512
#define C_DIM  16384
#define TEMP_INV 20.0f

typedef __bf16 bf16x8 __attribute__((ext_vector_type(8)));
typedef float  f32x4  __attribute__((ext_vector_type(4)));

__device__ __forceinline__ unsigned short f2bf(float x) {
    unsigned int u = __float_as_uint(x);
    unsigned int r = (u + 0x7FFFu + ((u >> 16) & 1u)) >> 16;  // RNE
    return (unsigned short)r;
}

__device__ __forceinline__ void async16(const void* g, void* l) {
    __builtin_amdgcn_global_load_lds(
        (const __attribute__((address_space(1))) void*)g,
        (__attribute__((address_space(3))) void*)l, 16, 0, 0);
}

// ---------------------------------------------------------------------------
// prep: blocks [0, C/4)        -> class_map row-norm + bf16 convert
//       blocks [C/4, C/4+512)  -> batch & teacher fp32 -> bf16
// ---------------------------------------------------------------------------
__global__ __launch_bounds__(256)
void prep_kernel(const float* __restrict__ cm, unsigned short* __restrict__ wbf,
                 float* __restrict__ inv_norm,
                 const float* __restrict__ batch, const float* __restrict__ teacher,
                 unsigned short* __restrict__ bbf, unsigned short* __restrict__ tbf) {
    if (blockIdx.x < C_DIM / 4) {
        int row  = blockIdx.x * 4 + (threadIdx.x >> 6);
        int lane = threadIdx.x & 63;
        const float4* r = (const float4*)(cm + (size_t)row * E_DIM);
        float4 v0 = r[lane * 2 + 0];
        float4 v1 = r[lane * 2 + 1];
        float ss = v0.x*v0.x + v0.y*v0.y + v0.z*v0.z + v0.w*v0.w
                 + v1.x*v1.x + v1.y*v1.y + v1.z*v1.z + v1.w*v1.w;
        for (int m = 32; m; m >>= 1) ss += __shfl_xor(ss, m);
        float inv = 1.0f / sqrtf(ss);
        if (lane == 0) inv_norm[row] = inv;
        uint4 pk;
        pk.x = (unsigned)f2bf(v0.x*inv) | ((unsigned)f2bf(v0.y*inv) << 16);
        pk.y = (unsigned)f2bf(v0.z*inv) | ((unsigned)f2bf(v0.w*inv) << 16);
        pk.z = (unsigned)f2bf(v1.x*inv) | ((unsigned)f2bf(v1.y*inv) << 16);
        pk.w = (unsigned)f2bf(v1.z*inv) | ((unsigned)f2bf(v1.w*inv) << 16);
        *(uint4*)(wbf + (size_t)row * E_DIM + lane * 8) = pk;
    } else {
        int idx = (blockIdx.x - C_DIM / 4) * 256 + threadIdx.x;  // 131072 threads
        {
            const float4* pa = (const float4*)batch;
            float4 v0 = pa[idx * 2], v1 = pa[idx * 2 + 1];
            uint4 pk;
            pk.x = (unsigned)f2bf(v0.x) | ((unsigned)f2bf(v0.y) << 16);
            pk.y = (unsigned)f2bf(v0.z) | ((unsigned)f2bf(v0.w) << 16);
            pk.z = (unsigned)f2bf(v1.x) | ((unsigned)f2bf(v1.y) << 16);
            pk.w = (unsigned)f2bf(v1.z) | ((unsigned)f2bf(v1.w) << 16);
            ((uint4*)bbf)[idx] = pk;
        }
        {
            const float4* pb = (const float4*)teacher;
            float4 v0 = pb[idx * 2], v1 = pb[idx * 2 + 1];
            uint4 pk;
            pk.x = (unsigned)f2bf(v0.x) | ((unsigned)f2bf(v0.y) << 16);
            pk.y = (unsigned)f2bf(v0.z) | ((unsigned)f2bf(v0.w) << 16);
            pk.z = (unsigned)f2bf(v1.x) | ((unsigned)f2bf(v1.y) << 16);
            pk.w = (unsigned)f2bf(v1.z) | ((unsigned)f2bf(v1.w) << 16);
            ((uint4*)tbf)[idx] = pk;
        }
    }
}

// ---------------------------------------------------------------------------
// bf16 MFMA GEMM core, C = A * B^T, both operands row-major K-contiguous.
// 128x128 tile, BK=64, 4 waves, 4x4 mfma_f32_16x16x32_bf16 per wave.
// LDS K-chunk XOR swizzle (chunk' = chunk ^ (row&7)) kills the 16-way bank
// conflict of the naive row*BK layout (verified R1->R2: conflicts 1.26e7 -> 0).
// EPI=0: store raw fp32 dots.  EPI=1: per-row (max,sumexp) over 64-col chunks.
// ---------------------------------------------------------------------------
#define BM 128
#define BN 128
#define BK 64

template <int EPI>
__device__ __forceinline__
void gemm_core(const unsigned short* __restrict__ A, const unsigned short* __restrict__ Bm,
               int K, int N, float* __restrict__ out, float scale,
               int bx, int by, unsigned short* lA, unsigned short* lB) {
    int tid = threadIdx.x;
    int w = tid >> 6, lane = tid & 63;
    int wr = w >> 1, wc = w & 1;
    int q = lane >> 4, c = lane & 15;

    f32x4 acc[4][4] = {};

    const unsigned short* Abase = A + (size_t)(by * BM) * K;
    const unsigned short* Bbase = Bm + (size_t)(bx * BN) * K;

    for (int kt = 0; kt < K; kt += BK) {
        #pragma unroll
        for (int cc = 0; cc < 4; cc++) {
            int f = cc * 256 + tid;
            int row = f >> 3, kcb = f & 7;
            int g = kcb ^ (row & 7);                       // swizzled source chunk
            async16(Abase + (size_t)row * K + kt + g * 8, (char*)lA + (size_t)f * 16);
        }
        #pragma unroll
        for (int cc = 0; cc < 4; cc++) {
            int f = cc * 256 + tid;
            int row = f >> 3, kcb = f & 7;
            int g = kcb ^ (row & 7);
            async16(Bbase + (size_t)row * K + kt + g * 8, (char*)lB + (size_t)f * 16);
        }
        __syncthreads();
        #pragma unroll
        for (int kk = 0; kk < BK; kk += 32) {
            int cb = (kk >> 3) + q;                        // logical chunk 0..7
            int sw = cb ^ (c & 7);                         // swizzled LDS chunk
            bf16x8 af[4], bfr[4];
            #pragma unroll
            for (int i = 0; i < 4; i++)
                af[i] = *(const bf16x8*)&lA[(wr * 64 + i * 16 + c) * BK + sw * 8];
            #pragma unroll
            for (int j = 0; j < 4; j++)
                bfr[j] = *(const bf16x8*)&lB[(wc * 64 + j * 16 + c) * BK + sw * 8];
            #pragma unroll
            for (int i = 0; i < 4; i++)
                #pragma unroll
                for (int j = 0; j < 4; j++)
                    acc[i][j] = __builtin_amdgcn_mfma_f32_16x16x32_bf16(af[i], bfr[j], acc[i][j], 0, 0, 0);
        }
        __syncthreads();
    }

    if (EPI == 0) {
        #pragma unroll
        for (int i = 0; i < 4; i++) {
            #pragma unroll
            for (int r = 0; r < 4; r++) {
                size_t row = (size_t)(by * BM + wr * 64 + i * 16 + q * 4 + r);
                float* o = out + row * N + bx * BN + wc * 64 + c;
                #pragma unroll
                for (int j = 0; j < 4; j++) o[j * 16] = acc[i][j][r];
            }
        }
    } else {
        int nch = N >> 6;
        float2* part = (float2*)out;
        #pragma unroll
        for (int i = 0; i < 4; i++) {
            #pragma unroll
            for (int r = 0; r < 4; r++) {
                int row = by * BM + wr * 64 + i * 16 + q * 4 + r;
                float z0 = acc[i][0][r] * scale, z1 = acc[i][1][r] * scale;
                float z2 = acc[i][2][r] * scale, z3 = acc[i][3][r] * scale;
                float mx = fmaxf(fmaxf(z0, z1), fmaxf(z2, z3));
                #pragma unroll
                for (int m = 1; m < 16; m <<= 1) mx = fmaxf(mx, __shfl_xor(mx, m));
                float s = __expf(z0 - mx) + __expf(z1 - mx) + __expf(z2 - mx) + __expf(z3 - mx);
                #pragma unroll
                for (int m = 1; m < 16; m <<= 1) s += __shfl_xor(s, m);
                if (c == 0) {
                    float2 v; v.x = mx; v.y = s;
                    part[(size_t)row * nch + bx * 2 + wc] = v;
                }
            }
        }
    }
}

__global__ __launch_bounds__(256)
void gemm_logits(const unsigned short* __restrict__ A, const unsigned short* __restrict__ Bm,
                 float* __restrict__ out) {
    __shared__ __align__(16) unsigned short lA[BM * BK];
    __shared__ __align__(16) unsigned short lB[BN * BK];
    gemm_core<1>(A, Bm, E_DIM, C_DIM, out, TEMP_INV, blockIdx.x, blockIdx.y, lA, lB);
}

// both self-similarity GEMMs in one dispatch (blockIdx.z selects operand)
__global__ __launch_bounds__(256)
void gemm_sims(const unsigned short* __restrict__ bbf, const unsigned short* __restrict__ tbf,
               float* __restrict__ sim, float* __restrict__ tsim) {
    __shared__ __align__(16) unsigned short lA[BM * BK];
    __shared__ __align__(16) unsigned short lB[BN * BK];
    const unsigned short* A = blockIdx.z ? tbf : bbf;
    float* out = blockIdx.z ? tsim : sim;
    gemm_core<0>(A, A, E_DIM, B_ROWS, out, 1.0f, blockIdx.x, blockIdx.y, lA, lB);
}

// ---------------------------------------------------------------------------
// reduce: blocks [0,512)      -> rank stage2 -> rank_part[row] (NO atomics)
//         blocks [512,2560)   -> KD row softmax/KL -> kd_part[row]
// Per-row partial writes replace the single-address atomicAdd that serialized
// R2's reduce at ~25ns/atomic x 2560 = 57us.
// ---------------------------------------------------------------------------
__global__ __launch_bounds__(256)
void reduce_kernel(const float2* __restrict__ part, const float* __restrict__ batch,
                   const float* __restrict__ cm, const float* __restrict__ inv_norm,
                   const int* __restrict__ labels,
                   const float* __restrict__ sim, const float* __restrict__ tsim,
                   float* __restrict__ rank_part, float* __restrict__ kd_part) {
    __shared__ float redmax[2][4];
    __shared__ float redsum[3][4];
    if (blockIdx.x < B_ROWS / 4) {
        int row  = blockIdx.x * 4 + (threadIdx.x >> 6);
        int lane = threadIdx.x & 63;
        const float2* p = part + (size_t)row * 256;
        float m[4], s[4];
        float M = -1e30f;
        #pragma unroll
        for (int t = 0; t < 4; t++) {
            float2 v = p[t * 64 + lane];
            m[t] = v.x; s[t] = v.y;
            M = fmaxf(M, v.x);
        }
        for (int msk = 32; msk; msk >>= 1) M = fmaxf(M, __shfl_xor(M, msk));
        float S = 0.f;
        #pragma unroll
        for (int t = 0; t < 4; t++) S += s[t] * __expf(m[t] - M);
        for (int msk = 32; msk; msk >>= 1) S += __shfl_xor(S, msk);
        float lse = M + logf(S);

        int li = labels[row];
        const float4* brow = (const float4*)(batch + (size_t)row * E_DIM);
        const float4* crow = (const float4*)(cm + (size_t)li * E_DIM);
        float d = 0.f;
        #pragma unroll
        for (int t = 0; t < 2; t++) {
            float4 a = brow[lane * 2 + t];
            float4 cv = crow[lane * 2 + t];
            d += a.x * cv.x + a.y * cv.y + a.z * cv.z + a.w * cv.w;
        }
        for (int msk = 32; msk; msk >>= 1) d += __shfl_xor(d, msk);
        float zl = d * inv_norm[li] * TEMP_INV;
        if (lane == 0) rank_part[row] = lse - zl;
    } else {
        int i = blockIdx.x - B_ROWS / 4;
        int tid = threadIdx.x;
        int w = tid >> 6, lane = tid & 63;
        int li = labels[i];
        const float4* srow = (const float4*)(sim + (size_t)i * B_ROWS);
        const float4* trow = (const float4*)(tsim + (size_t)i * B_ROWS);
        const int4*   lab4 = (const int4*)labels;

        float a[8], b[8];
        float ms = -1e30f, mt = -1e30f;
        #pragma unroll
        for (int k = 0; k < 2; k++) {
            int j4 = tid + k * 256;
            float4 zs4 = srow[j4];
            float4 zt4 = trow[j4];
            int4   lb  = lab4[j4];
            float sc0 = (lb.x == li) ? 0.25f : 0.125f;   // scale/TAU
            float sc1 = (lb.y == li) ? 0.25f : 0.125f;
            float sc2 = (lb.z == li) ? 0.25f : 0.125f;
            float sc3 = (lb.w == li) ? 0.25f : 0.125f;
            a[k*4+0] = zs4.x * sc0; b[k*4+0] = zt4.x * sc0;
            a[k*4+1] = zs4.y * sc1; b[k*4+1] = zt4.y * sc1;
            a[k*4+2] = zs4.z * sc2; b[k*4+2] = zt4.z * sc2;
            a[k*4+3] = zs4.w * sc3; b[k*4+3] = zt4.w * sc3;
        }
        #pragma unroll
        for (int k = 0; k < 8; k++) { ms = fmaxf(ms, a[k]); mt = fmaxf(mt, b[k]); }
        for (int msk = 32; msk; msk >>= 1) { ms = fmaxf(ms, __shfl_xor(ms, msk)); mt = fmaxf(mt, __shfl_xor(mt, msk)); }
        if (lane == 0) { redmax[0][w] = ms; redmax[1][w] = mt; }
        __syncthreads();
        float Ms = fmaxf(fmaxf(redmax[0][0], redmax[0][1]), fmaxf(redmax[0][2], redmax[0][3]));
        float Mt = fmaxf(fmaxf(redmax[1][0], redmax[1][1]), fmaxf(redmax[1][2], redmax[1][3]));

        float Ss = 0.f, St = 0.f, U = 0.f;
        #pragma unroll
        for (int k = 0; k < 8; k++) {
            float ds = a[k] - Ms, dt = b[k] - Mt;
            float et = __expf(dt);
            Ss += __expf(ds);
            St += et;
            U  += et * (dt - ds);
        }
        for (int msk = 32; msk; msk >>= 1) { Ss += __shfl_xor(Ss, msk); St += __shfl_xor(St, msk); U += __shfl_xor(U, msk); }
        if (lane == 0) { redsum[0][w] = Ss; redsum[1][w] = St; redsum[2][w] = U; }
        __syncthreads();
        if (tid == 0) {
            float SsT = redsum[0][0] + redsum[0][1] + redsum[0][2] + redsum[0][3];
            float StT = redsum[1][0] + redsum[1][1] + redsum[1][2] + redsum[1][3];
            float UT  = redsum[2][0] + redsum[2][1] + redsum[2][2] + redsum[2][3];
            kd_part[i] = UT / StT - (logf(StT) - logf(SsT));
        }
    }
}

// single 256-thread block sums the 2x2048 partials
__global__ __launch_bounds__(256)
void finalize_kernel(const float* __restrict__ rank_part, const float* __restrict__ kd_part,
                     const int* __restrict__ epoch, float* __restrict__ out) {
    __shared__ float red[2][4];
    int tid = threadIdx.x, w = tid >> 6, lane = tid & 63;
    float sr = 0.f, sk = 0.f;
    const float4* rp = (const float4*)rank_part;
    const float4* kp = (const float4*)kd_part;
    #pragma unroll
    for (int k = 0; k < 2; k++) {
        float4 a = rp[tid + k * 256]; sr += a.x + a.y + a.z + a.w;
        float4 b = kp[tid + k * 256]; sk += b.x + b.y + b.z + b.w;
    }
    for (int m = 32; m; m >>= 1) { sr += __shfl_xor(sr, m); sk += __shfl_xor(sk, m); }
    if (lane == 0) { red[0][w] = sr; red[1][w] = sk; }
    __syncthreads();
    if (tid == 0) {
        float lr = (red[0][0] + red[0][1] + red[0][2] + red[0][3]) * (1.0f / (float)B_ROWS);
        float lk = (red[1][0] + red[1][1] + red[1][2] + red[1][3]) * (1.0f / (float)B_ROWS);
        float ramp = ((float)epoch[0] / 150.0f) * 16.0f;  // ALPHA * TAU^2
        out[0] = lr + ramp * lk;
        out[1] = lr;
        out[2] = lk;
    }
}

// ---------------------------------------------------------------------------
extern "C" void kernel_launch(void* const* d_in, const int* in_sizes, int n_in,
                              void* d_out, int out_size, void* d_ws, size_t ws_size,
                              hipStream_t stream) {
    const float* batch   = (const float*)d_in[0];
    const float* teacher = (const float*)d_in[1];
    const float* cm      = (const float*)d_in[2];
    const int*   labels  = (const int*)d_in[3];
    const int*   epoch   = (const int*)d_in[4];
    float* out = (float*)d_out;
    char* ws = (char*)d_ws;

    // workspace layout (all 256-aligned)
    float*          inv_norm = (float*)(ws + 0);                     // 64 KB
    unsigned short* wbf      = (unsigned short*)(ws + 65536);        // 16 MB
    unsigned short* bbf      = (unsigned short*)(ws + 16842752);     // 2 MB
    unsigned short* tbf      = (unsigned short*)(ws + 18939904);     // 2 MB
    float*          part     = (float*)(ws + 21037056);              // 4 MB (float2[2048][256])
    float*          sim      = (float*)(ws + 25231360);              // 16 MB
    float*          tsim     = (float*)(ws + 42008576);              // 16 MB
    // partials overlay the wbf region (dead after gemm_logits)
    float*          rank_part = (float*)(ws + 65536);                // 8 KB
    float*          kd_part   = (float*)(ws + 65536 + 8192);         // 8 KB

    prep_kernel<<<C_DIM / 4 + 512, 256, 0, stream>>>(cm, wbf, inv_norm, batch, teacher, bbf, tbf);

    gemm_logits<<<dim3(C_DIM / BN, B_ROWS / BM), 256, 0, stream>>>(bbf, wbf, (float*)part);

    gemm_sims<<<dim3(B_ROWS / BN, B_ROWS / BM, 2), 256, 0, stream>>>(bbf, tbf, sim, tsim);

    reduce_kernel<<<B_ROWS / 4 + B_ROWS, 256, 0, stream>>>(
        (const float2*)part, batch, cm, inv_norm, labels, sim, tsim, rank_part, kd_part);

    finalize_kernel<<<1, 256, 0, stream>>>(rank_part, kd_part, epoch, out);
}